// Round 3
// baseline (4217.652 us; speedup 1.0000x reference)
//
#include <hip/hip_runtime.h>
#include <math.h>

#define NODE 5
#define TT 512
#define NBATCH 8192
#define NB 16            // batch elems per block (N dim = one 16-col MFMA tile)
#define LDT 144          // padded row stride (halfs): 288B rows -> conflict-free b128/b64
#define TB 16            // time steps staged per x-chunk
#define XS_DIM 325
#define H2 256
#define EPS 1e-5f

typedef _Float16 h16;
typedef __attribute__((ext_vector_type(8))) _Float16 half8;
typedef __attribute__((ext_vector_type(4))) _Float16 half4v;
typedef __attribute__((ext_vector_type(4))) float float4v;

// ---------------------------------------------------------------------------
// RNN kernel, weights-as-A-operand formulation.
//   D[m=out_feat][n=batch] = W^T[m][k] * act[k][n]
// C-layout: lane ln = batch col, q*4+r = out feats -> the 5x5 node mix is a
// per-lane f32 register op across the 5 node accumulators (no LDS, no
// cross-lane). Activations live in LDS as sT[node][batch][feat] rows; frags
// are 1x ds_read_b128 each, epilogue writes are 1x ds_write_b64 each.
// 3 barriers/step (layer ping-pong), adj in SGPRs with uniform zero-skip.
// ---------------------------------------------------------------------------
__global__ __launch_bounds__(256, 2) void rnn_kernel(
    const float* __restrict__ x, const float* __restrict__ adj,
    const float* __restrict__ W0, const float* __restrict__ b0,
    const float* __restrict__ W1, const float* __restrict__ b1,
    const float* __restrict__ W2, const float* __restrict__ b2,
    float* __restrict__ xs)
{
    __shared__ __align__(16) h16 sT[2][NODE][NB][LDT];   // 46080 B, ping-pong
    __shared__ h16 sx[2][NB][NODE][TB + 2];              //  5760 B, x chunks

    const int tid  = threadIdx.x;
    const int lane = tid & 63;
    const int w    = tid >> 6;     // wave 0..3
    const int ln   = lane & 15;    // batch col
    const int q    = lane >> 4;    // quad: k-offset q*8 (frags), rows q*4.. (C)
    const int k0q  = q * 8;
    const int bbase = blockIdx.x * NB;

    // ---- A = adj.T, forced uniform (SGPR) so mix branches are scalar ----
    float af[NODE][NODE];
    #pragma unroll
    for (int i = 0; i < NODE; ++i)
        #pragma unroll
        for (int j = 0; j < NODE; ++j)
            af[i][j] = __int_as_float(
                __builtin_amdgcn_readfirstlane(__float_as_int(adj[j*NODE + i])));

    // ---- weight A-fragments (registers, whole kernel) ----
    // A-frag: lane holds W^T[m = ln (+16*mt)][k = k0q + j]
    half8 wA0[2][2];   // [mtile][ktile]  W0 rows 1..64 (state part), M=128
    half8 wA1[2][4];   //                 W1, K=128, M=128
    half8 wA2[4];      //                 W2, K=128, M=64 (mtile = w)
    #pragma unroll
    for (int i2 = 0; i2 < 2; ++i2) {
        const int m = (2*w + i2)*16 + ln;
        #pragma unroll
        for (int ks = 0; ks < 2; ++ks) {
            half8 f;
            #pragma unroll
            for (int j = 0; j < 8; ++j)
                f[j] = (h16)W0[(size_t)(1 + ks*32 + k0q + j)*128 + m];
            wA0[i2][ks] = f;
        }
        #pragma unroll
        for (int ks = 0; ks < 4; ++ks) {
            half8 f;
            #pragma unroll
            for (int j = 0; j < 8; ++j)
                f[j] = (h16)W1[(size_t)(ks*32 + k0q + j)*128 + m];
            wA1[i2][ks] = f;
        }
    }
    #pragma unroll
    for (int ks = 0; ks < 4; ++ks) {
        half8 f;
        #pragma unroll
        for (int j = 0; j < 8; ++j)
            f[j] = (h16)W2[(size_t)(ks*32 + k0q + j)*64 + w*16 + ln];
        wA2[ks] = f;
    }
    // per-thread bias / W0-row0 (indexed by out-feat = rows q*4+r of C tile)
    float b0r[2][4], w0r[2][4], b1r[2][4], b2r[4];
    #pragma unroll
    for (int i2 = 0; i2 < 2; ++i2)
        #pragma unroll
        for (int r = 0; r < 4; ++r) {
            int m = (2*w + i2)*16 + q*4 + r;
            b0r[i2][r] = b0[m];
            w0r[i2][r] = W0[m];          // W0 row 0
            b1r[i2][r] = b1[m];
        }
    #pragma unroll
    for (int r = 0; r < 4; ++r) b2r[r] = b2[w*16 + q*4 + r];

    // ---- zero initial state region of sT[0] (feats 0..63) ----
    {
        half4v z4 = {(h16)0.f,(h16)0.f,(h16)0.f,(h16)0.f};
        for (int idx = tid; idx < NODE*NB*16; idx += 256) {
            int rr = idx >> 4, c4 = idx & 15;
            *(half4v*)&sT[0][rr >> 4][rr & 15][c4*4] = z4;
        }
    }
    // ---- stage x chunk 0 ----
    {
        #pragma unroll
        for (int k = 0; k < 5; ++k) {
            int i = tid + k*256;               // 0..1279
            int t = i & 15, n = (i >> 4) % 5, e = i / 80;
            sx[0][e][n][t] = (h16)x[((size_t)(bbase+e)*NODE + n)*TT + t];
        }
    }
    __syncthreads();

    int cur = 0;
    #pragma unroll 1
    for (int t = 0; t < TT; ++t) {
        const int tc = t >> 4, tt = t & 15;
        if (tt == 0 && tc + 1 < TT/TB) {       // prefetch next x chunk
            #pragma unroll
            for (int k = 0; k < 5; ++k) {
                int i = tid + k*256;
                int t2 = i & 15, n = (i >> 4) % 5, e = i / 80;
                sx[(tc+1)&1][e][n][t2] =
                    (h16)x[((size_t)(bbase+e)*NODE + n)*TT + (tc+1)*TB + t2];
            }
        }

        // ================= L1: h1 = relu(A(cat(x,s)@W0) + b0) =============
        {
            const h16 (*Ti)[NB][LDT] = sT[cur];
            h16 (*To)[NB][LDT] = sT[cur^1];
            float xv[NODE], xm[NODE];
            #pragma unroll
            for (int j = 0; j < NODE; ++j) xv[j] = (float)sx[tc&1][ln][j][tt];
            #pragma unroll
            for (int i = 0; i < NODE; ++i) {
                float s = 0.f;
                #pragma unroll
                for (int j = 0; j < NODE; ++j)
                    if (af[i][j] != 0.f) s += af[i][j]*xv[j];
                xm[i] = s;
            }
            float4v acc[NODE][2];
            #pragma unroll
            for (int j = 0; j < NODE; ++j) {
                half8 bf0 = *(const half8*)&Ti[j][ln][k0q];
                half8 bf1 = *(const half8*)&Ti[j][ln][32 + k0q];
                #pragma unroll
                for (int i2 = 0; i2 < 2; ++i2) {
                    float4v a = {0.f,0.f,0.f,0.f};
                    a = __builtin_amdgcn_mfma_f32_16x16x32_f16(wA0[i2][0], bf0, a, 0,0,0);
                    a = __builtin_amdgcn_mfma_f32_16x16x32_f16(wA0[i2][1], bf1, a, 0,0,0);
                    acc[j][i2] = a;
                }
            }
            #pragma unroll
            for (int i = 0; i < NODE; ++i)
                #pragma unroll
                for (int i2 = 0; i2 < 2; ++i2) {
                    float g[4] = {0.f,0.f,0.f,0.f};
                    #pragma unroll
                    for (int j = 0; j < NODE; ++j)
                        if (af[i][j] != 0.f) {
                            #pragma unroll
                            for (int r = 0; r < 4; ++r) g[r] += af[i][j]*acc[j][i2][r];
                        }
                    half4v o;
                    #pragma unroll
                    for (int r = 0; r < 4; ++r) {
                        float v = g[r] + b0r[i2][r] + w0r[i2][r]*xm[i];
                        o[r] = (h16)fmaxf(v, 0.f);
                    }
                    *(half4v*)&To[i][ln][(2*w + i2)*16 + q*4] = o;
                }
        }
        __syncthreads(); cur ^= 1;

        // ================= L2: h2 = relu(A(h1@W1) + b1) ===================
        {
            const h16 (*Ti)[NB][LDT] = sT[cur];
            h16 (*To)[NB][LDT] = sT[cur^1];
            float4v acc[NODE][2];
            #pragma unroll
            for (int j = 0; j < NODE; ++j) {
                half8 bf[4];
                #pragma unroll
                for (int ks = 0; ks < 4; ++ks)
                    bf[ks] = *(const half8*)&Ti[j][ln][ks*32 + k0q];
                #pragma unroll
                for (int i2 = 0; i2 < 2; ++i2) {
                    float4v a = {0.f,0.f,0.f,0.f};
                    #pragma unroll
                    for (int ks = 0; ks < 4; ++ks)
                        a = __builtin_amdgcn_mfma_f32_16x16x32_f16(wA1[i2][ks], bf[ks], a, 0,0,0);
                    acc[j][i2] = a;
                }
            }
            #pragma unroll
            for (int i = 0; i < NODE; ++i)
                #pragma unroll
                for (int i2 = 0; i2 < 2; ++i2) {
                    float g[4] = {0.f,0.f,0.f,0.f};
                    #pragma unroll
                    for (int j = 0; j < NODE; ++j)
                        if (af[i][j] != 0.f) {
                            #pragma unroll
                            for (int r = 0; r < 4; ++r) g[r] += af[i][j]*acc[j][i2][r];
                        }
                    half4v o;
                    #pragma unroll
                    for (int r = 0; r < 4; ++r)
                        o[r] = (h16)fmaxf(g[r] + b1r[i2][r], 0.f);
                    *(half4v*)&To[i][ln][(2*w + i2)*16 + q*4] = o;
                }
        }
        __syncthreads(); cur ^= 1;

        // ================= L3: s = tanh(A(h2@W2) + b2) ====================
        {
            const h16 (*Ti)[NB][LDT] = sT[cur];
            h16 (*To)[NB][LDT] = sT[cur^1];
            float4v acc3[NODE];
            #pragma unroll
            for (int j = 0; j < NODE; ++j) {
                half8 bf[4];
                #pragma unroll
                for (int ks = 0; ks < 4; ++ks)
                    bf[ks] = *(const half8*)&Ti[j][ln][ks*32 + k0q];
                float4v a = {0.f,0.f,0.f,0.f};
                #pragma unroll
                for (int ks = 0; ks < 4; ++ks)
                    a = __builtin_amdgcn_mfma_f32_16x16x32_f16(wA2[ks], bf[ks], a, 0,0,0);
                acc3[j] = a;
            }
            #pragma unroll
            for (int i = 0; i < NODE; ++i) {
                float g[4] = {0.f,0.f,0.f,0.f};
                #pragma unroll
                for (int j = 0; j < NODE; ++j)
                    if (af[i][j] != 0.f) {
                        #pragma unroll
                        for (int r = 0; r < 4; ++r) g[r] += af[i][j]*acc3[j][r];
                    }
                half4v o;
                #pragma unroll
                for (int r = 0; r < 4; ++r) {
                    float z = g[r] + b2r[r];
                    float e = __expf(-2.f*fabsf(z));
                    o[r] = (h16)copysignf((1.f - e)/(1.f + e), z);
                }
                *(half4v*)&To[i][ln][w*16 + q*4] = o;
            }
        }
        __syncthreads(); cur ^= 1;
    }

    // ---- epilogue: xs[b] = [x_end(5) | state(5*64)] ----
    {
        const int e = tid >> 4, f = tid & 15;
        const size_t ob = (size_t)(bbase + e)*XS_DIM;
        #pragma unroll
        for (int n = 0; n < NODE; ++n) {
            half4v hv = *(const half4v*)&sT[cur][n][e][f*4];
            #pragma unroll
            for (int c = 0; c < 4; ++c)
                xs[ob + 5 + n*64 + f*4 + c] = (float)hv[c];
        }
        if (f < NODE)
            xs[ob + f] = (float)sx[1][e][f][15];   // chunk 31 -> buf 1, tt=15
    }
}

// ---------------------------------------------------------------------------
// Kernel B: h = relu(xs @ fc1_w + fc1_b) + per-column sum/sumsq for BN.
// ---------------------------------------------------------------------------
__global__ __launch_bounds__(256) void fc1_kernel(
    const float* __restrict__ xs, const float* __restrict__ fc1_w,
    const float* __restrict__ fc1_b, float* __restrict__ h,
    float* __restrict__ sums)
{
    __shared__ float s_xs[16*XS_DIM];
    const int tid = threadIdx.x;
    const int r0 = blockIdx.x * 16;
    for (int i = tid; i < 16*XS_DIM; i += 256)
        s_xs[i] = xs[(size_t)r0*XS_DIM + i];
    __syncthreads();

    float acc[16];
    #pragma unroll
    for (int r = 0; r < 16; ++r) acc[r] = 0.f;
    for (int k = 0; k < XS_DIM; ++k) {
        float wv = fc1_w[(size_t)k*H2 + tid];
        #pragma unroll
        for (int r = 0; r < 16; ++r) acc[r] += s_xs[r*XS_DIM + k]*wv;
    }
    float bb = fc1_b[tid];
    float ls = 0.f, lq = 0.f;
    #pragma unroll
    for (int r = 0; r < 16; ++r) {
        float v = fmaxf(acc[r] + bb, 0.f);
        h[(size_t)(r0+r)*H2 + tid] = v;
        ls += v; lq += v*v;
    }
    atomicAdd(&sums[tid], ls);
    atomicAdd(&sums[H2 + tid], lq);
}

// ---------------------------------------------------------------------------
// Kernel C: BN(train) normalize + fc2 + softmax. One wave per row.
// ---------------------------------------------------------------------------
__global__ __launch_bounds__(256) void head_kernel(
    const float* __restrict__ h, const float* __restrict__ sums,
    const float* __restrict__ gamma, const float* __restrict__ beta,
    const float* __restrict__ fc2_w, const float* __restrict__ fc2_b,
    float* __restrict__ out)
{
    const int lane = threadIdx.x & 63;
    const int r = blockIdx.x*4 + (threadIdx.x >> 6);
    const int c0 = lane*4;

    float4 hv = *(const float4*)&h[(size_t)r*H2 + c0];
    float hvv[4] = {hv.x, hv.y, hv.z, hv.w};
    float y[4];
    #pragma unroll
    for (int c = 0; c < 4; ++c) {
        int cc = c0 + c;
        float mean = sums[cc] * (1.f/NBATCH);
        float var  = sums[H2+cc]*(1.f/NBATCH) - mean*mean;
        float rstd = rsqrtf(var + EPS);
        y[c] = (hvv[c] - mean)*rstd*gamma[cc] + beta[cc];
    }
    float lg[7];
    #pragma unroll
    for (int j = 0; j < 7; ++j) {
        float p = 0.f;
        #pragma unroll
        for (int c = 0; c < 4; ++c) p += y[c]*fc2_w[(size_t)(c0+c)*7 + j];
        #pragma unroll
        for (int off = 32; off >= 1; off >>= 1) p += __shfl_xor(p, off, 64);
        lg[j] = p + fc2_b[j];
    }
    if (lane == 0) {
        float m = lg[0];
        #pragma unroll
        for (int j = 1; j < 7; ++j) m = fmaxf(m, lg[j]);
        float ev[7]; float s = 0.f;
        #pragma unroll
        for (int j = 0; j < 7; ++j) { ev[j] = expf(lg[j]-m); s += ev[j]; }
        float inv = 1.f/s;
        #pragma unroll
        for (int j = 0; j < 7; ++j) out[(size_t)r*7 + j] = ev[j]*inv;
    }
}

// ---------------------------------------------------------------------------
extern "C" void kernel_launch(void* const* d_in, const int* in_sizes, int n_in,
                              void* d_out, int out_size, void* d_ws, size_t ws_size,
                              hipStream_t stream)
{
    (void)in_sizes; (void)n_in; (void)out_size; (void)ws_size;
    const float* x     = (const float*)d_in[0];
    const float* adj   = (const float*)d_in[1];
    const float* W0    = (const float*)d_in[2];
    const float* b0    = (const float*)d_in[3];
    const float* W1    = (const float*)d_in[4];
    const float* b1    = (const float*)d_in[5];
    const float* W2    = (const float*)d_in[6];
    const float* b2    = (const float*)d_in[7];
    const float* fc1w  = (const float*)d_in[8];
    const float* fc1b  = (const float*)d_in[9];
    const float* gamma = (const float*)d_in[10];
    const float* beta  = (const float*)d_in[11];
    const float* fc2w  = (const float*)d_in[12];
    const float* fc2b  = (const float*)d_in[13];
    float* out = (float*)d_out;

    char* ws = (char*)d_ws;
    float* xs   = (float*)(ws);                                  // 8192*325 f32
    float* hbuf = (float*)(ws + 10649600);                       // 8192*256 f32
    float* sums = (float*)(ws + 10649600 + 8388608);             // 512 f32

    hipMemsetAsync(sums, 0, 512*sizeof(float), stream);
    rnn_kernel<<<NBATCH/NB, 256, 0, stream>>>(x, adj, W0, b0, W1, b1, W2, b2, xs);
    fc1_kernel<<<NBATCH/16, 256, 0, stream>>>(xs, fc1w, fc1b, hbuf, sums);
    head_kernel<<<NBATCH/4, 256, 0, stream>>>(hbuf, sums, gamma, beta, fc2w, fc2b, out);
}

// Round 4
// 3685.497 us; speedup vs baseline: 1.1444x; 1.1444x over previous
//
#include <hip/hip_runtime.h>
#include <math.h>

#define NODE 5
#define TT 512
#define NBATCH 8192
#define NB 32            // batch elems per block: 2 MFMA n-tiles
#define TB 16            // time steps staged per x-chunk
#define XS_DIM 325
#define H2 256
#define EPS 1e-5f

typedef _Float16 h16;
typedef __attribute__((ext_vector_type(8))) _Float16 half8;
typedef __attribute__((ext_vector_type(4))) _Float16 half4v;
typedef __attribute__((ext_vector_type(4))) float float4v;

// ---------------------------------------------------------------------------
// RNN kernel. 4 waves = (M-half mh) x (n-tile nt). Activations live in LDS in
// *packed MFMA B-fragment order*: elem (k, col) of node nd at
//   nd*K*32 + nt*K*16 + (k>>5)*512 + lane(k,col)*8 + (k&7),  lane = ((k>>3)&3)*16 + (col&15)
// so a wave's frag read is 64 contiguous 16B chunks (conflict-free) and all
// addressing is one base reg + immediate offsets. adj entries are exactly
// 0/1 -> node mix = conditional adds under a uniform SGPR bitmask.
// 1 block/CU (112KB LDS), 1 wave/SIMD, VGPR budget 512 (weights held in regs).
// ---------------------------------------------------------------------------
__global__ __launch_bounds__(256, 1) void rnn_kernel(
    const float* __restrict__ x, const float* __restrict__ adj,
    const float* __restrict__ W0, const float* __restrict__ b0,
    const float* __restrict__ W1, const float* __restrict__ b1,
    const float* __restrict__ W2, const float* __restrict__ b2,
    float* __restrict__ xs)
{
    __shared__ __align__(16) h16 bufS[NODE*2048];   // state, K=64   (20480 B)
    __shared__ __align__(16) h16 buf1[NODE*4096];   // h1,    K=128  (40960 B)
    __shared__ __align__(16) h16 buf2[NODE*4096];   // h2,    K=128  (40960 B)
    __shared__ h16 sx[2][TB][NODE][NB];             // x chunks      (10240 B)

    const int tid  = threadIdx.x;
    const int lane = tid & 63;
    const int wv   = tid >> 6;
    const int mh   = wv >> 1;        // M-half: 0 -> feats 0..63, 1 -> 64..127
    const int nt   = wv & 1;         // n-tile: cols nt*16 .. nt*16+15
    const int ln   = lane & 15;
    const int q    = lane >> 4;
    const int bbase = blockIdx.x * NB;

    // ---- adjacency bitmask (A = adj.T, entries exactly 0/1), uniform ----
    unsigned am = 0;
    #pragma unroll
    for (int i = 0; i < NODE; ++i)
        #pragma unroll
        for (int j = 0; j < NODE; ++j)
            if (adj[j*NODE + i] > 0.5f) am |= 1u << (i*NODE + j);
    const unsigned amask = __builtin_amdgcn_readfirstlane(am);

    // ---- weight A-fragments in registers (128 VGPR) ----
    half8 wA0[4][2], wA1[4][4], wA2[2][4];
    #pragma unroll
    for (int mt = 0; mt < 4; ++mt) {
        const int m = mh*64 + mt*16 + ln;
        #pragma unroll
        for (int ks = 0; ks < 2; ++ks) {
            half8 f;
            #pragma unroll
            for (int j = 0; j < 8; ++j)
                f[j] = (h16)W0[(size_t)(1 + ks*32 + q*8 + j)*128 + m];  // rows 1..64
            wA0[mt][ks] = f;
        }
        #pragma unroll
        for (int ks = 0; ks < 4; ++ks) {
            half8 f;
            #pragma unroll
            for (int j = 0; j < 8; ++j)
                f[j] = (h16)W1[(size_t)(ks*32 + q*8 + j)*128 + m];
            wA1[mt][ks] = f;
        }
    }
    #pragma unroll
    for (int mt = 0; mt < 2; ++mt) {
        const int m3 = mh*32 + mt*16 + ln;
        #pragma unroll
        for (int ks = 0; ks < 4; ++ks) {
            half8 f;
            #pragma unroll
            for (int j = 0; j < 8; ++j)
                f[j] = (h16)W2[(size_t)(ks*32 + q*8 + j)*64 + m3];
            wA2[mt][ks] = f;
        }
    }
    // per-thread bias / W0-row0 scalars (indexed by out-feat rows of C tile)
    float b0r[4][4], w0r[4][4], b1r[4][4], b2r[2][4];
    #pragma unroll
    for (int mt = 0; mt < 4; ++mt)
        #pragma unroll
        for (int r = 0; r < 4; ++r) {
            const int fm = mh*64 + mt*16 + q*4 + r;
            b0r[mt][r] = b0[fm];
            w0r[mt][r] = W0[fm];           // W0 row 0 (x rank-1 term)
            b1r[mt][r] = b1[fm];
        }
    #pragma unroll
    for (int mt = 0; mt < 2; ++mt)
        #pragma unroll
        for (int r = 0; r < 4; ++r) b2r[mt][r] = b2[mh*32 + mt*16 + q*4 + r];

    // ---- address bases (computed once; everything else is immediates) ----
    const int rbaseS = nt*1024 + lane*8;
    const int rbase1 = nt*2048 + lane*8;
    const int wbase1 = nt*2048 + mh*1024 + (q>>1)*128 + (q&1)*4 + ln*8;
    const int wbaseS = nt*1024 + mh*512  + (q>>1)*128 + (q&1)*4 + ln*8;

    // ---- zero initial state; stage x chunk 0 ----
    for (int i = tid; i < NODE*2048/2; i += 256) ((unsigned*)bufS)[i] = 0u;
    #pragma unroll
    for (int k2 = 0; k2 < 10; ++k2) {
        int i = tid + k2*256;              // 0..2559
        int t2 = i & 15, bn = i >> 4;      // bn 0..159
        int b = bn / 5, n = bn - b*5;
        sx[0][t2][n][b] = (h16)x[((size_t)(bbase+b)*NODE + n)*TT + t2];
    }
    __syncthreads();

    #pragma unroll 1
    for (int t = 0; t < TT; ++t) {
        const int tc = t >> 4, tt = t & 15;
        if (tt == 0 && tc + 1 < TT/TB) {   // prefetch next x chunk
            #pragma unroll
            for (int k2 = 0; k2 < 10; ++k2) {
                int i = tid + k2*256;
                int t2 = i & 15, bn = i >> 4;
                int b = bn / 5, n = bn - b*5;
                sx[(tc+1)&1][t2][n][b] =
                    (h16)x[((size_t)(bbase+b)*NODE + n)*TT + (tc+1)*TB + t2];
            }
        }

        // ============ L1: h1 = relu( A(cat(x,s)@W0) + b0 ) ================
        {
            float xv[NODE], xm[NODE];
            #pragma unroll
            for (int j = 0; j < NODE; ++j) xv[j] = (float)sx[tc&1][tt][j][nt*16+ln];
            #pragma unroll
            for (int i = 0; i < NODE; ++i) {
                float s = 0.f;
                #pragma unroll
                for (int j = 0; j < NODE; ++j)
                    if (amask & (1u << (i*NODE + j))) s += xv[j];
                xm[i] = s;
            }
            float4v acc[NODE][4];
            #pragma unroll
            for (int j = 0; j < NODE; ++j) {
                half8 bf0 = *(const half8*)&bufS[j*2048 + rbaseS];
                half8 bf1 = *(const half8*)&bufS[j*2048 + rbaseS + 512];
                #pragma unroll
                for (int mt = 0; mt < 4; ++mt) {
                    float4v a = {0.f,0.f,0.f,0.f};
                    a = __builtin_amdgcn_mfma_f32_16x16x32_f16(wA0[mt][0], bf0, a, 0,0,0);
                    a = __builtin_amdgcn_mfma_f32_16x16x32_f16(wA0[mt][1], bf1, a, 0,0,0);
                    acc[j][mt] = a;
                }
            }
            #pragma unroll
            for (int i = 0; i < NODE; ++i) {
                float g[4][4];
                #pragma unroll
                for (int mt = 0; mt < 4; ++mt)
                    #pragma unroll
                    for (int r = 0; r < 4; ++r)
                        g[mt][r] = b0r[mt][r] + w0r[mt][r]*xm[i];
                #pragma unroll
                for (int j = 0; j < NODE; ++j)
                    if (amask & (1u << (i*NODE + j))) {
                        #pragma unroll
                        for (int mt = 0; mt < 4; ++mt)
                            #pragma unroll
                            for (int r = 0; r < 4; ++r) g[mt][r] += acc[j][mt][r];
                    }
                #pragma unroll
                for (int mt = 0; mt < 4; ++mt) {
                    half4v o;
                    #pragma unroll
                    for (int r = 0; r < 4; ++r) o[r] = (h16)fmaxf(g[mt][r], 0.f);
                    *(half4v*)&buf1[i*4096 + wbase1 + (mt>>1)*512 + (mt&1)*256] = o;
                }
            }
        }
        __syncthreads();

        // ============ L2: h2 = relu( A(h1@W1) + b1 ) ======================
        {
            float4v acc[NODE][4];
            #pragma unroll
            for (int j = 0; j < NODE; ++j) {
                half8 bf[4];
                #pragma unroll
                for (int ks = 0; ks < 4; ++ks)
                    bf[ks] = *(const half8*)&buf1[j*4096 + rbase1 + ks*512];
                #pragma unroll
                for (int mt = 0; mt < 4; ++mt) {
                    float4v a = {0.f,0.f,0.f,0.f};
                    #pragma unroll
                    for (int ks = 0; ks < 4; ++ks)
                        a = __builtin_amdgcn_mfma_f32_16x16x32_f16(wA1[mt][ks], bf[ks], a, 0,0,0);
                    acc[j][mt] = a;
                }
            }
            #pragma unroll
            for (int i = 0; i < NODE; ++i) {
                float g[4][4];
                #pragma unroll
                for (int mt = 0; mt < 4; ++mt)
                    #pragma unroll
                    for (int r = 0; r < 4; ++r) g[mt][r] = b1r[mt][r];
                #pragma unroll
                for (int j = 0; j < NODE; ++j)
                    if (amask & (1u << (i*NODE + j))) {
                        #pragma unroll
                        for (int mt = 0; mt < 4; ++mt)
                            #pragma unroll
                            for (int r = 0; r < 4; ++r) g[mt][r] += acc[j][mt][r];
                    }
                #pragma unroll
                for (int mt = 0; mt < 4; ++mt) {
                    half4v o;
                    #pragma unroll
                    for (int r = 0; r < 4; ++r) o[r] = (h16)fmaxf(g[mt][r], 0.f);
                    *(half4v*)&buf2[i*4096 + wbase1 + (mt>>1)*512 + (mt&1)*256] = o;
                }
            }
        }
        __syncthreads();

        // ============ L3: s = tanh( A(h2@W2) + b2 ) =======================
        {
            float4v acc[NODE][2];
            #pragma unroll
            for (int j = 0; j < NODE; ++j) {
                half8 bf[4];
                #pragma unroll
                for (int ks = 0; ks < 4; ++ks)
                    bf[ks] = *(const half8*)&buf2[j*4096 + rbase1 + ks*512];
                #pragma unroll
                for (int mt = 0; mt < 2; ++mt) {
                    float4v a = {0.f,0.f,0.f,0.f};
                    #pragma unroll
                    for (int ks = 0; ks < 4; ++ks)
                        a = __builtin_amdgcn_mfma_f32_16x16x32_f16(wA2[mt][ks], bf[ks], a, 0,0,0);
                    acc[j][mt] = a;
                }
            }
            #pragma unroll
            for (int i = 0; i < NODE; ++i) {
                float g[2][4];
                #pragma unroll
                for (int mt = 0; mt < 2; ++mt)
                    #pragma unroll
                    for (int r = 0; r < 4; ++r) g[mt][r] = b2r[mt][r];
                #pragma unroll
                for (int j = 0; j < NODE; ++j)
                    if (amask & (1u << (i*NODE + j))) {
                        #pragma unroll
                        for (int mt = 0; mt < 2; ++mt)
                            #pragma unroll
                            for (int r = 0; r < 4; ++r) g[mt][r] += acc[j][mt][r];
                    }
                #pragma unroll
                for (int mt = 0; mt < 2; ++mt) {
                    half4v o;
                    #pragma unroll
                    for (int r = 0; r < 4; ++r) {
                        float z = g[mt][r];
                        float e2 = __expf(2.f*z);        // overflow->inf is fine
                        o[r] = (h16)(1.f - 2.f/(e2 + 1.f));
                    }
                    *(half4v*)&bufS[i*2048 + wbaseS + mt*256] = o;
                }
            }
        }
        __syncthreads();
    }

    // ---- epilogue: xs[b] = [x_end(5) | state(5*64)] ----
    {
        const int e = tid >> 3, f8 = tid & 7;    // e: batch 0..31, f8: feat/8
        const size_t ob = (size_t)(bbase + e)*XS_DIM;
        const int rb = (e>>4)*1024 + (f8>>2)*512 + (f8&3)*128 + (e&15)*8;
        #pragma unroll
        for (int n = 0; n < NODE; ++n) {
            half8 hv = *(const half8*)&bufS[n*2048 + rb];
            #pragma unroll
            for (int c = 0; c < 8; ++c)
                xs[ob + 5 + n*64 + f8*8 + c] = (float)hv[c];
        }
    }
    if (tid < NB*NODE) {
        int e = tid / 5, n = tid - e*5;
        xs[(size_t)(bbase+e)*XS_DIM + n] = (float)sx[1][15][n][e];  // x[...,511]
    }
}

// ---------------------------------------------------------------------------
// Kernel B: h = relu(xs @ fc1_w + fc1_b) + per-column sum/sumsq for BN.
// ---------------------------------------------------------------------------
__global__ __launch_bounds__(256) void fc1_kernel(
    const float* __restrict__ xs, const float* __restrict__ fc1_w,
    const float* __restrict__ fc1_b, float* __restrict__ h,
    float* __restrict__ sums)
{
    __shared__ float s_xs[16*XS_DIM];
    const int tid = threadIdx.x;
    const int r0 = blockIdx.x * 16;
    for (int i = tid; i < 16*XS_DIM; i += 256)
        s_xs[i] = xs[(size_t)r0*XS_DIM + i];
    __syncthreads();

    float acc[16];
    #pragma unroll
    for (int r = 0; r < 16; ++r) acc[r] = 0.f;
    for (int k = 0; k < XS_DIM; ++k) {
        float wv = fc1_w[(size_t)k*H2 + tid];
        #pragma unroll
        for (int r = 0; r < 16; ++r) acc[r] += s_xs[r*XS_DIM + k]*wv;
    }
    float bb = fc1_b[tid];
    float ls = 0.f, lq = 0.f;
    #pragma unroll
    for (int r = 0; r < 16; ++r) {
        float v = fmaxf(acc[r] + bb, 0.f);
        h[(size_t)(r0+r)*H2 + tid] = v;
        ls += v; lq += v*v;
    }
    atomicAdd(&sums[tid], ls);
    atomicAdd(&sums[H2 + tid], lq);
}

// ---------------------------------------------------------------------------
// Kernel C: BN(train) normalize + fc2 + softmax. One wave per row.
// ---------------------------------------------------------------------------
__global__ __launch_bounds__(256) void head_kernel(
    const float* __restrict__ h, const float* __restrict__ sums,
    const float* __restrict__ gamma, const float* __restrict__ beta,
    const float* __restrict__ fc2_w, const float* __restrict__ fc2_b,
    float* __restrict__ out)
{
    const int lane = threadIdx.x & 63;
    const int r = blockIdx.x*4 + (threadIdx.x >> 6);
    const int c0 = lane*4;

    float4 hv = *(const float4*)&h[(size_t)r*H2 + c0];
    float hvv[4] = {hv.x, hv.y, hv.z, hv.w};
    float y[4];
    #pragma unroll
    for (int c = 0; c < 4; ++c) {
        int cc = c0 + c;
        float mean = sums[cc] * (1.f/NBATCH);
        float var  = sums[H2+cc]*(1.f/NBATCH) - mean*mean;
        float rstd = rsqrtf(var + EPS);
        y[c] = (hvv[c] - mean)*rstd*gamma[cc] + beta[cc];
    }
    float lg[7];
    #pragma unroll
    for (int j = 0; j < 7; ++j) {
        float p = 0.f;
        #pragma unroll
        for (int c = 0; c < 4; ++c) p += y[c]*fc2_w[(size_t)(c0+c)*7 + j];
        #pragma unroll
        for (int off = 32; off >= 1; off >>= 1) p += __shfl_xor(p, off, 64);
        lg[j] = p + fc2_b[j];
    }
    if (lane == 0) {
        float m = lg[0];
        #pragma unroll
        for (int j = 1; j < 7; ++j) m = fmaxf(m, lg[j]);
        float ev[7]; float s = 0.f;
        #pragma unroll
        for (int j = 0; j < 7; ++j) { ev[j] = expf(lg[j]-m); s += ev[j]; }
        float inv = 1.f/s;
        #pragma unroll
        for (int j = 0; j < 7; ++j) out[(size_t)r*7 + j] = ev[j]*inv;
    }
}

// ---------------------------------------------------------------------------
extern "C" void kernel_launch(void* const* d_in, const int* in_sizes, int n_in,
                              void* d_out, int out_size, void* d_ws, size_t ws_size,
                              hipStream_t stream)
{
    (void)in_sizes; (void)n_in; (void)out_size; (void)ws_size;
    const float* x     = (const float*)d_in[0];
    const float* adj   = (const float*)d_in[1];
    const float* W0    = (const float*)d_in[2];
    const float* b0    = (const float*)d_in[3];
    const float* W1    = (const float*)d_in[4];
    const float* b1    = (const float*)d_in[5];
    const float* W2    = (const float*)d_in[6];
    const float* b2    = (const float*)d_in[7];
    const float* fc1w  = (const float*)d_in[8];
    const float* fc1b  = (const float*)d_in[9];
    const float* gamma = (const float*)d_in[10];
    const float* beta  = (const float*)d_in[11];
    const float* fc2w  = (const float*)d_in[12];
    const float* fc2b  = (const float*)d_in[13];
    float* out = (float*)d_out;

    char* ws = (char*)d_ws;
    float* xs   = (float*)(ws);                                  // 8192*325 f32
    float* hbuf = (float*)(ws + 10649600);                       // 8192*256 f32
    float* sums = (float*)(ws + 10649600 + 8388608);             // 512 f32

    hipMemsetAsync(sums, 0, 512*sizeof(float), stream);
    rnn_kernel<<<NBATCH/NB, 256, 0, stream>>>(x, adj, W0, b0, W1, b1, W2, b2, xs);
    fc1_kernel<<<NBATCH/16, 256, 0, stream>>>(xs, fc1w, fc1b, hbuf, sums);
    head_kernel<<<NBATCH/4, 256, 0, stream>>>(hbuf, sums, gamma, beta, fc2w, fc2b, out);
}